// Round 4
// baseline (334.099 us; speedup 1.0000x reference)
//
#include <hip/hip_runtime.h>
#include <hip/hip_bf16.h>
#include <cstdint>

#define NQ 256
#define NK 2048
#define BB 2
#define SCALE 0.17677669529663687f  // 32^-0.5

// ws byte offsets (16B aligned)
#define TB_OFF 0u         // f16[64000]   tables [i][z][y][x][h]          128000 B
#define QP_OFF 128000u    // float[131072]  q-proj (B,nQ,256), pre-scaled 524288 B
#define KT_OFF 652288u    // float[131072]  k-proj transposed (B,32,nK)   524288 B
#define VT_OFF 1176576u   // float[131072]  v-proj transposed (B,32,nK)   524288 B
#define X_OFF  1700864u   // float[2][131072] attn@v k-split partials     1 MB

typedef unsigned short u16;
typedef _Float16 h16;
union U16x8 { uint4 u; h16 h[8]; };

// ---------------- kernel 0: fused prep (tables + kv-proj + q-proj) ----------------
// blocks [0,256): kv-proj   [256,320): q-proj   [320,328): cpb tables
__global__ __launch_bounds__(512) void k_prep(const float* __restrict__ query,
                                              const float* __restrict__ key,
                                              const float* __restrict__ qw,
                                              const float* __restrict__ qb,
                                              const float* __restrict__ kw,
                                              const float* __restrict__ kb,
                                              const float* __restrict__ vw,
                                              const float* __restrict__ vb,
                                              const float* __restrict__ w1g,
                                              const float* __restrict__ b1g,
                                              const float* __restrict__ w2g,
                                              u16* __restrict__ tb,
                                              float* __restrict__ qp,
                                              float* __restrict__ kpT,
                                              float* __restrict__ vT) {
  __shared__ __align__(16) char smraw[16 * 257 * 4];
  int bid = blockIdx.x, t = threadIdx.x;

  if (bid < 256) {
    // ---- kv-proj: kpT[b][d][k], vT[b][d][k] (both LDS-transposed) ----
    float (*rows)[257] = (float(*)[257])smraw;
    int b = bid >> 7, kc = bid & 127;
    for (int idx = t; idx < 4096; idx += 512) {
      int r = idx >> 8, m = idx & 255;
      rows[r][m] = key[((kc * 16 + r) * BB + b) * 256 + m];
    }
    __syncthreads();
    int ks = t >> 5, d = t & 31;
    float a = kb[d], av = vb[d];
    #pragma unroll 4
    for (int m = 0; m < 256; ++m) {
      float rv = rows[ks][m];
      a  = fmaf(rv, kw[m * 32 + d], a);
      av = fmaf(rv, vw[m * 32 + d], av);
    }
    __syncthreads();                       // rows no longer needed
    float* f1 = (float*)smraw;             // 512 floats
    float* f2 = f1 + 512;                  // 512 floats
    f1[d * 16 + ks] = a;
    f2[d * 16 + ks] = av;
    __syncthreads();
    int dd = t >> 4, kk = t & 15;          // 512 threads cover 32x16
    int ko = kc * 16 + kk;
    kpT[(b * 32 + dd) * NK + ko] = f1[dd * 16 + kk];
    vT [(b * 32 + dd) * NK + ko] = f2[dd * 16 + kk];
  } else if (bid < 320) {
    // ---- q-proj (pre-scaled): 8 rows per block ----
    float (*rows)[257] = (float(*)[257])smraw;
    int qg = bid - 256;  // 0..63, 8 global rows each
    for (int idx = t; idx < 2048; idx += 512) {
      int r = idx >> 8, m = idx & 255;
      int g = qg * 8 + r, b = g >> 8, q = g & 255;
      rows[r][m] = query[(q * BB + b) * 256 + m];
    }
    __syncthreads();
    int r = t >> 6, c0 = (t & 63) * 4;
    int g = qg * 8 + r;
    float4 acc = *(const float4*)&qb[c0];
    #pragma unroll 4
    for (int m = 0; m < 256; ++m) {
      float rv = rows[r][m];
      float4 w4 = *(const float4*)&qw[m * 256 + c0];
      acc.x = fmaf(rv, w4.x, acc.x); acc.y = fmaf(rv, w4.y, acc.y);
      acc.z = fmaf(rv, w4.z, acc.z); acc.w = fmaf(rv, w4.w, acc.w);
    }
    float4 o; o.x = acc.x * SCALE; o.y = acc.y * SCALE; o.z = acc.z * SCALE; o.w = acc.w * SCALE;
    *(float4*)&qp[g * 256 + c0] = o;
  } else {
    // ---- cpb tables (f16): one i per block ----
    float* w1 = (float*)smraw;          // 384
    float* b1 = w1 + 384;               // 128
    float* w2 = b1 + 128;               // 1024
    int i = bid - 320;
    for (int idx = t; idx < 384; idx += 512) w1[idx] = w1g[i * 384 + idx];
    if (t < 128) b1[t] = b1g[i * 128 + t];
    for (int idx = t; idx < 1024; idx += 512) w2[idx] = w2g[i * 1024 + idx];
    __syncthreads();
    for (int cell = t; cell < 1000; cell += 512) {
      int z = cell / 100, y = (cell / 10) % 10, x = cell % 10;
      const float step = 8.0f / 9.0f;
      float cz = -4.f + z * step, cy = -4.f + y * step, cx = -4.f + x * step;
      float o0 = 0, o1 = 0, o2 = 0, o3 = 0, o4 = 0, o5 = 0, o6 = 0, o7 = 0;
      for (int d = 0; d < 128; ++d) {
        float h = fmaxf(fmaf(cz, w1[d], fmaf(cy, w1[128 + d], fmaf(cx, w1[256 + d], b1[d]))), 0.f);
        const float* w2r = &w2[d * 8];
        o0 = fmaf(h, w2r[0], o0); o1 = fmaf(h, w2r[1], o1);
        o2 = fmaf(h, w2r[2], o2); o3 = fmaf(h, w2r[3], o3);
        o4 = fmaf(h, w2r[4], o4); o5 = fmaf(h, w2r[5], o5);
        o6 = fmaf(h, w2r[6], o6); o7 = fmaf(h, w2r[7], o7);
      }
      U16x8 R;
      R.h[0] = (h16)o0; R.h[1] = (h16)o1; R.h[2] = (h16)o2; R.h[3] = (h16)o3;
      R.h[4] = (h16)o4; R.h[5] = (h16)o5; R.h[6] = (h16)o6; R.h[7] = (h16)o7;
      *(uint4*)&tb[i * 8000 + cell * 8] = R.u;
    }
  }
}

// ---------------- kernel 1: fused qk + rpe + softmax -> attn ----------------
struct Axis { int o0, o1; float w0, w1; };

static __device__ __forceinline__ Axis axis_setup(float dv, int stride) {
  float g = copysignf(__log2f(fmaf(fabsf(dv), 512.f, 1.f)) * (1.f / 12.f), dv);
  float p = fmaf(g, 4.5f, 4.5f);
  float f = floorf(p);
  int i0 = (int)f;
  float w1v = p - f;
  float w0v = 1.f - w1v;
  Axis a;
  a.w0 = ((unsigned)i0 <= 9u) ? w0v : 0.f;
  a.w1 = ((unsigned)(i0 + 1) <= 9u) ? w1v : 0.f;
  int c0 = min(max(i0, 0), 9);
  int c1 = min(max(i0 + 1, 0), 9);
  a.o0 = c0 * stride;
  a.o1 = c1 * stride;
  return a;
}

// f16 table read: (float)h fused into v_fma_mix_f32 by the compiler
#define DO_CORNER(CU, W, J) do { float ww = (W); \
  acc[0][J] = fmaf((float)(CU).h[0], ww, acc[0][J]); \
  acc[1][J] = fmaf((float)(CU).h[1], ww, acc[1][J]); \
  acc[2][J] = fmaf((float)(CU).h[2], ww, acc[2][J]); \
  acc[3][J] = fmaf((float)(CU).h[3], ww, acc[3][J]); \
  acc[4][J] = fmaf((float)(CU).h[4], ww, acc[4][J]); \
  acc[5][J] = fmaf((float)(CU).h[5], ww, acc[5][J]); \
  acc[6][J] = fmaf((float)(CU).h[6], ww, acc[6][J]); \
  acc[7][J] = fmaf((float)(CU).h[7], ww, acc[7][J]); } while (0)

__global__ __launch_bounds__(1024, 4) void k_main(const u16* __restrict__ tbw,
                                                  const float* __restrict__ qp,
                                                  const float* __restrict__ kpT,
                                                  const float* __restrict__ xyz,
                                                  const float* __restrict__ refp,
                                                  float* __restrict__ attn) {
  __shared__ __align__(16) u16 tb[64000];     // 125 KB f16 tables
  __shared__ __align__(16) float qrow[2][256];
  __shared__ __align__(16) float rp[2][24];
  __shared__ __align__(16) float red[2][64];  // [qh][h][wave8]
  int t = threadIdx.x;
  int b = blockIdx.x >> 7, qc = blockIdx.x & 127;
  for (int idx = t; idx < 8000; idx += 1024)
    ((uint4*)tb)[idx] = ((const uint4*)tbw)[idx];
  if (t < 128) {
    int qh2 = t >> 6, c = t & 63;
    ((float4*)qrow[qh2])[c] = ((const float4*)(qp + (b * 256 + qc * 2 + qh2) * 256))[c];
  } else if (t < 140) {
    int idx = t - 128;                 // 12 float4s cover rp[2][24]
    int qh2 = idx / 6, c = idx % 6;
    ((float4*)rp[qh2])[c] = ((const float4*)(refp + (b * 256 + qc * 2 + qh2) * 24))[c];
  }
  __syncthreads();

  int wv = t >> 6, l = t & 63;
  int qh = wv >> 3, wvl = wv & 7;
  int q = qc * 2 + qh;
  int k0 = wvl * 256 + l * 4;          // 4 consecutive k per thread
  float acc[8][4] = {};

  // phase 1: qk^T (q pre-scaled)
  const float* kT = kpT + b * (32 * NK);
  #pragma unroll 2
  for (int dq = 0; dq < 8; ++dq) {
    const float* kp0 = kT + (dq * 4) * NK + k0;
    float4 kv0 = *(const float4*)(kp0);
    float4 kv1 = *(const float4*)(kp0 + NK);
    float4 kv2 = *(const float4*)(kp0 + 2 * NK);
    float4 kv3 = *(const float4*)(kp0 + 3 * NK);
    #pragma unroll
    for (int h = 0; h < 8; ++h) {
      float4 qv = *(const float4*)&qrow[qh][h * 32 + dq * 4];
      acc[h][0] = fmaf(qv.x, kv0.x, fmaf(qv.y, kv1.x, fmaf(qv.z, kv2.x, fmaf(qv.w, kv3.x, acc[h][0]))));
      acc[h][1] = fmaf(qv.x, kv0.y, fmaf(qv.y, kv1.y, fmaf(qv.z, kv2.y, fmaf(qv.w, kv3.y, acc[h][1]))));
      acc[h][2] = fmaf(qv.x, kv0.z, fmaf(qv.y, kv1.z, fmaf(qv.z, kv2.z, fmaf(qv.w, kv3.z, acc[h][2]))));
      acc[h][3] = fmaf(qv.x, kv0.w, fmaf(qv.y, kv1.w, fmaf(qv.z, kv2.w, fmaf(qv.w, kv3.w, acc[h][3]))));
    }
  }

  // phase 2: rpe trilinear sampling, accumulate into logits
  {
    const float* xp = xyz + (size_t)(b * NK + k0) * 3;
    float4 X0 = *(const float4*)(xp);
    float4 X1 = *(const float4*)(xp + 4);
    float4 X2 = *(const float4*)(xp + 8);
    float xv[4] = { X0.x, X0.w, X1.z, X2.y };
    float yv[4] = { X0.y, X1.x, X1.w, X2.z };
    float zv[4] = { X0.z, X1.y, X2.x, X2.w };
    #pragma unroll 1
    for (int i = 0; i < 8; ++i) {
      float rx = rp[qh][i * 3 + 0];
      float ry = rp[qh][i * 3 + 1];
      float rz = rp[qh][i * 3 + 2];
      const u16* tp = tb + i * 8000;
      #pragma unroll
      for (int j = 0; j < 4; ++j) {
        Axis ax = axis_setup(rx - xv[j], 8);
        Axis ay = axis_setup(ry - yv[j], 80);
        Axis az = axis_setup(rz - zv[j], 800);
        float w00 = az.w0 * ay.w0, w01 = az.w0 * ay.w1;
        float w10 = az.w1 * ay.w0, w11 = az.w1 * ay.w1;
        U16x8 u;
        u.u = *(const uint4*)(tp + az.o0 + ay.o0 + ax.o0); DO_CORNER(u, w00 * ax.w0, j);
        u.u = *(const uint4*)(tp + az.o0 + ay.o0 + ax.o1); DO_CORNER(u, w00 * ax.w1, j);
        u.u = *(const uint4*)(tp + az.o0 + ay.o1 + ax.o0); DO_CORNER(u, w01 * ax.w0, j);
        u.u = *(const uint4*)(tp + az.o0 + ay.o1 + ax.o1); DO_CORNER(u, w01 * ax.w1, j);
        u.u = *(const uint4*)(tp + az.o1 + ay.o0 + ax.o0); DO_CORNER(u, w10 * ax.w0, j);
        u.u = *(const uint4*)(tp + az.o1 + ay.o0 + ax.o1); DO_CORNER(u, w10 * ax.w1, j);
        u.u = *(const uint4*)(tp + az.o1 + ay.o1 + ax.o0); DO_CORNER(u, w11 * ax.w0, j);
        u.u = *(const uint4*)(tp + az.o1 + ay.o1 + ax.o1); DO_CORNER(u, w11 * ax.w1, j);
      }
    }
  }

  // phase 3: softmax over k (2048) per head, within each wave-half (8 waves)
  float mx[8];
  #pragma unroll
  for (int h = 0; h < 8; ++h) {
    float m = fmaxf(fmaxf(acc[h][0], acc[h][1]), fmaxf(acc[h][2], acc[h][3]));
    #pragma unroll
    for (int off = 32; off >= 1; off >>= 1) m = fmaxf(m, __shfl_xor(m, off, 64));
    mx[h] = m;
  }
  if (l == 0) {
    #pragma unroll
    for (int h = 0; h < 8; ++h) red[qh][h * 8 + wvl] = mx[h];
  }
  __syncthreads();
  #pragma unroll
  for (int h = 0; h < 8; ++h) {
    float4 r0 = *(const float4*)&red[qh][h * 8];
    float4 r1 = *(const float4*)&red[qh][h * 8 + 4];
    mx[h] = fmaxf(fmaxf(fmaxf(r0.x, r0.y), fmaxf(r0.z, r0.w)),
                  fmaxf(fmaxf(r1.x, r1.y), fmaxf(r1.z, r1.w)));
  }
  __syncthreads();
  float sm[8];
  #pragma unroll
  for (int h = 0; h < 8; ++h) {
    acc[h][0] = __expf(acc[h][0] - mx[h]);
    acc[h][1] = __expf(acc[h][1] - mx[h]);
    acc[h][2] = __expf(acc[h][2] - mx[h]);
    acc[h][3] = __expf(acc[h][3] - mx[h]);
    float s = (acc[h][0] + acc[h][1]) + (acc[h][2] + acc[h][3]);
    #pragma unroll
    for (int off = 32; off >= 1; off >>= 1) s += __shfl_xor(s, off, 64);
    sm[h] = s;
  }
  if (l == 0) {
    #pragma unroll
    for (int h = 0; h < 8; ++h) red[qh][h * 8 + wvl] = sm[h];
  }
  __syncthreads();
  #pragma unroll
  for (int h = 0; h < 8; ++h) {
    float4 r0 = *(const float4*)&red[qh][h * 8];
    float4 r1 = *(const float4*)&red[qh][h * 8 + 4];
    float s = ((r0.x + r0.y) + (r0.z + r0.w)) + ((r1.x + r1.y) + (r1.z + r1.w));
    float inv = 1.f / s;
    float4 pv;
    pv.x = acc[h][0] * inv; pv.y = acc[h][1] * inv;
    pv.z = acc[h][2] * inv; pv.w = acc[h][3] * inv;
    *(float4*)&attn[((b * 8 + h) * 256 + q) * 2048 + k0] = pv;
  }
}

// ---------------- kernel 2: x = attn @ v (k-split x2, vT both-float4) ----------------
__global__ __launch_bounds__(256) void k_av(const float* __restrict__ attn,
                                            const float* __restrict__ vT,
                                            float* __restrict__ xpart) {
  int bid = blockIdx.x;  // 1024 = b(2) x h(8) x qt(32) x kh(2)
  int kh = bid & 1, qt = (bid >> 1) & 31, h = (bid >> 6) & 7, b = bid >> 9;
  int t = threadIdx.x;
  int rq = t >> 5, d = t & 31;
  int q = qt * 8 + rq;
  const float* ar = attn + ((size_t)((b * 8 + h) * 256 + q)) * 2048 + kh * 1024;
  const float* vr = vT + (size_t)(b * 32 + d) * 2048 + kh * 1024;
  float a0 = 0, a1 = 0, a2 = 0, a3 = 0, a4 = 0, a5 = 0, a6 = 0, a7 = 0;
  #pragma unroll 4
  for (int k = 0; k < 1024; k += 8) {
    float4 p0 = *(const float4*)&ar[k];
    float4 p1 = *(const float4*)&ar[k + 4];
    float4 v0 = *(const float4*)&vr[k];
    float4 v1 = *(const float4*)&vr[k + 4];
    a0 = fmaf(p0.x, v0.x, a0); a1 = fmaf(p0.y, v0.y, a1);
    a2 = fmaf(p0.z, v0.z, a2); a3 = fmaf(p0.w, v0.w, a3);
    a4 = fmaf(p1.x, v1.x, a4); a5 = fmaf(p1.y, v1.y, a5);
    a6 = fmaf(p1.z, v1.z, a6); a7 = fmaf(p1.w, v1.w, a7);
  }
  float s = ((a0 + a1) + (a2 + a3)) + ((a4 + a5) + (a6 + a7));
  xpart[kh * 131072 + (b * 256 + q) * 256 + h * 32 + d] = s;
}

// ---------------- kernel 3: out = (xpart0+xpart1) @ proj_w + proj_b ----------------
__global__ __launch_bounds__(256) void k_out(const float* __restrict__ xpart,
                                             const float* __restrict__ pw,
                                             const float* __restrict__ pb,
                                             float* __restrict__ out) {
  __shared__ float xr[4][257];
  int b = blockIdx.x >> 6, qc = blockIdx.x & 63, t = threadIdx.x;
  for (int idx = t; idx < 1024; idx += 256) {
    int r = idx >> 8, m = idx & 255;
    int q = qc * 4 + r;
    int o = (b * 256 + q) * 256 + m;
    xr[r][m] = xpart[o] + xpart[131072 + o];
  }
  __syncthreads();
  int r = t >> 6, c0 = (t & 63) * 4;
  float4 a = *(const float4*)&pb[c0];
  #pragma unroll 4
  for (int m = 0; m < 256; ++m) {
    float rv = xr[r][m];
    float4 w4 = *(const float4*)&pw[m * 256 + c0];
    a.x = fmaf(rv, w4.x, a.x); a.y = fmaf(rv, w4.y, a.y);
    a.z = fmaf(rv, w4.z, a.z); a.w = fmaf(rv, w4.w, a.w);
  }
  int q = qc * 4 + r;
  *(float4*)&out[(q * BB + b) * 256 + c0] = a;
}

// ---------------- launch ----------------
extern "C" void kernel_launch(void* const* d_in, const int* in_sizes, int n_in,
                              void* d_out, int out_size, void* d_ws, size_t ws_size,
                              hipStream_t stream) {
  const float* query = (const float*)d_in[0];
  const float* key   = (const float*)d_in[1];
  const float* refp  = (const float*)d_in[2];
  // d_in[3] reference_angle: unused by reference
  const float* xyz   = (const float*)d_in[4];
  const float* qw    = (const float*)d_in[5];
  const float* qb    = (const float*)d_in[6];
  const float* kw    = (const float*)d_in[7];
  const float* kb    = (const float*)d_in[8];
  const float* vw    = (const float*)d_in[9];
  const float* vb    = (const float*)d_in[10];
  const float* pw    = (const float*)d_in[11];
  const float* pb    = (const float*)d_in[12];
  const float* w1    = (const float*)d_in[13];
  const float* b1    = (const float*)d_in[14];
  const float* w2    = (const float*)d_in[15];

  char* ws = (char*)d_ws;
  u16*   tb    = (u16*)(ws + TB_OFF);
  float* qp    = (float*)(ws + QP_OFF);
  float* kpT   = (float*)(ws + KT_OFF);
  float* vT    = (float*)(ws + VT_OFF);
  float* xpart = (float*)(ws + X_OFF);
  float* out  = (float*)d_out;
  float* attn = out + 131072;  // second tuple output

  hipLaunchKernelGGL(k_prep, dim3(328),  dim3(512),  0, stream,
                     query, key, qw, qb, kw, kb, vw, vb, w1, b1, w2, tb, qp, kpT, vT);
  hipLaunchKernelGGL(k_main, dim3(256),  dim3(1024), 0, stream, tb, qp, kpT, xyz, refp, attn);
  hipLaunchKernelGGL(k_av,   dim3(1024), dim3(256),  0, stream, attn, vT, xpart);
  hipLaunchKernelGGL(k_out,  dim3(128),  dim3(256),  0, stream, xpart, pw, pb, out);
}

// Round 5
// 217.586 us; speedup vs baseline: 1.5355x; 1.5355x over previous
//
#include <hip/hip_runtime.h>
#include <hip/hip_bf16.h>
#include <cstdint>

#define NQ 256
#define NK 2048
#define BB 2
#define SCALE 0.17677669529663687f  // 32^-0.5

// ws byte offsets (16B aligned)
#define TB_OFF 0u         // f16[64000]   tables [i][z][y][x][h]          128000 B
#define QP_OFF 128000u    // float[131072]  q-proj (B,nQ,256), pre-scaled 524288 B
#define KT_OFF 652288u    // float[131072]  k-proj transposed (B,32,nK)   524288 B
#define VP_OFF 1176576u   // float[131072]  v-proj (B,nK,32)              524288 B
#define X_OFF  1700864u   // float[8][131072] attn@v k-split partials     4 MB

typedef unsigned short u16;
typedef _Float16 h16;
union U16x8 { uint4 u; h16 h[8]; };

// ---------------- kernel 0: fused prep (tables + kv-proj + q-proj) ----------------
// blocks [0,256): kv-proj   [256,320): q-proj   [320,328): cpb tables
__global__ __launch_bounds__(512) void k_prep(const float* __restrict__ query,
                                              const float* __restrict__ key,
                                              const float* __restrict__ qw,
                                              const float* __restrict__ qb,
                                              const float* __restrict__ kw,
                                              const float* __restrict__ kb,
                                              const float* __restrict__ vw,
                                              const float* __restrict__ vb,
                                              const float* __restrict__ w1g,
                                              const float* __restrict__ b1g,
                                              const float* __restrict__ w2g,
                                              u16* __restrict__ tb,
                                              float* __restrict__ qp,
                                              float* __restrict__ kpT,
                                              float* __restrict__ vp) {
  __shared__ __align__(16) char smraw[16 * 257 * 4];
  int bid = blockIdx.x, t = threadIdx.x;

  if (bid < 256) {
    // ---- kv-proj: kpT[b][d][k] (LDS-transposed), vp[b][k][d] (direct) ----
    float (*rows)[257] = (float(*)[257])smraw;
    int b = bid >> 7, kc = bid & 127;
    for (int idx = t; idx < 4096; idx += 512) {
      int r = idx >> 8, m = idx & 255;
      rows[r][m] = key[((kc * 16 + r) * BB + b) * 256 + m];
    }
    __syncthreads();
    int ks = t >> 5, d = t & 31;
    float a = kb[d], av = vb[d];
    #pragma unroll 4
    for (int m = 0; m < 256; ++m) {
      float rv = rows[ks][m];
      a  = fmaf(rv, kw[m * 32 + d], a);
      av = fmaf(rv, vw[m * 32 + d], av);
    }
    int k = kc * 16 + ks;
    vp[(b * NK + k) * 32 + d] = av;        // coalesced: d consecutive across lanes
    __syncthreads();                       // rows no longer needed
    float* f1 = (float*)smraw;             // 512 floats
    f1[d * 16 + ks] = a;
    __syncthreads();
    int dd = t >> 4, kk = t & 15;          // 512 threads cover 32x16
    kpT[(b * 32 + dd) * NK + kc * 16 + kk] = f1[dd * 16 + kk];
  } else if (bid < 320) {
    // ---- q-proj (pre-scaled): 8 rows per block ----
    float (*rows)[257] = (float(*)[257])smraw;
    int qg = bid - 256;  // 0..63, 8 global rows each
    for (int idx = t; idx < 2048; idx += 512) {
      int r = idx >> 8, m = idx & 255;
      int g = qg * 8 + r, b = g >> 8, q = g & 255;
      rows[r][m] = query[(q * BB + b) * 256 + m];
    }
    __syncthreads();
    int r = t >> 6, c0 = (t & 63) * 4;
    int g = qg * 8 + r;
    float4 acc = *(const float4*)&qb[c0];
    #pragma unroll 4
    for (int m = 0; m < 256; ++m) {
      float rv = rows[r][m];
      float4 w4 = *(const float4*)&qw[m * 256 + c0];
      acc.x = fmaf(rv, w4.x, acc.x); acc.y = fmaf(rv, w4.y, acc.y);
      acc.z = fmaf(rv, w4.z, acc.z); acc.w = fmaf(rv, w4.w, acc.w);
    }
    float4 o; o.x = acc.x * SCALE; o.y = acc.y * SCALE; o.z = acc.z * SCALE; o.w = acc.w * SCALE;
    *(float4*)&qp[g * 256 + c0] = o;
  } else {
    // ---- cpb tables (f16): one i per block ----
    float* w1 = (float*)smraw;          // 384
    float* b1 = w1 + 384;               // 128
    float* w2 = b1 + 128;               // 1024
    int i = bid - 320;
    for (int idx = t; idx < 384; idx += 512) w1[idx] = w1g[i * 384 + idx];
    if (t < 128) b1[t] = b1g[i * 128 + t];
    for (int idx = t; idx < 1024; idx += 512) w2[idx] = w2g[i * 1024 + idx];
    __syncthreads();
    for (int cell = t; cell < 1000; cell += 512) {
      int z = cell / 100, y = (cell / 10) % 10, x = cell % 10;
      const float step = 8.0f / 9.0f;
      float cz = -4.f + z * step, cy = -4.f + y * step, cx = -4.f + x * step;
      float o0 = 0, o1 = 0, o2 = 0, o3 = 0, o4 = 0, o5 = 0, o6 = 0, o7 = 0;
      for (int d = 0; d < 128; ++d) {
        float h = fmaxf(fmaf(cz, w1[d], fmaf(cy, w1[128 + d], fmaf(cx, w1[256 + d], b1[d]))), 0.f);
        const float* w2r = &w2[d * 8];
        o0 = fmaf(h, w2r[0], o0); o1 = fmaf(h, w2r[1], o1);
        o2 = fmaf(h, w2r[2], o2); o3 = fmaf(h, w2r[3], o3);
        o4 = fmaf(h, w2r[4], o4); o5 = fmaf(h, w2r[5], o5);
        o6 = fmaf(h, w2r[6], o6); o7 = fmaf(h, w2r[7], o7);
      }
      U16x8 R;
      R.h[0] = (h16)o0; R.h[1] = (h16)o1; R.h[2] = (h16)o2; R.h[3] = (h16)o3;
      R.h[4] = (h16)o4; R.h[5] = (h16)o5; R.h[6] = (h16)o6; R.h[7] = (h16)o7;
      *(uint4*)&tb[i * 8000 + cell * 8] = R.u;
    }
  }
}

// ---------------- kernel 1: fused qk + rpe + softmax -> attn ----------------
struct Axis { int o0, o1; float w0, w1; };

static __device__ __forceinline__ Axis axis_setup(float dv, int stride) {
  float g = copysignf(__log2f(fmaf(fabsf(dv), 512.f, 1.f)) * (1.f / 12.f), dv);
  float p = fmaf(g, 4.5f, 4.5f);
  float f = floorf(p);
  int i0 = (int)f;
  float w1v = p - f;
  float w0v = 1.f - w1v;
  Axis a;
  a.w0 = ((unsigned)i0 <= 9u) ? w0v : 0.f;
  a.w1 = ((unsigned)(i0 + 1) <= 9u) ? w1v : 0.f;
  int c0 = min(max(i0, 0), 9);
  int c1 = min(max(i0 + 1, 0), 9);
  a.o0 = c0 * stride;
  a.o1 = c1 * stride;
  return a;
}

// f16 table read: (float)h fused into v_fma_mix_f32 by the compiler
#define DO_CORNER(CU, W, J) do { float ww = (W); \
  acc[0][J] = fmaf((float)(CU).h[0], ww, acc[0][J]); \
  acc[1][J] = fmaf((float)(CU).h[1], ww, acc[1][J]); \
  acc[2][J] = fmaf((float)(CU).h[2], ww, acc[2][J]); \
  acc[3][J] = fmaf((float)(CU).h[3], ww, acc[3][J]); \
  acc[4][J] = fmaf((float)(CU).h[4], ww, acc[4][J]); \
  acc[5][J] = fmaf((float)(CU).h[5], ww, acc[5][J]); \
  acc[6][J] = fmaf((float)(CU).h[6], ww, acc[6][J]); \
  acc[7][J] = fmaf((float)(CU).h[7], ww, acc[7][J]); } while (0)

__global__ __launch_bounds__(1024, 4) void k_main(const u16* __restrict__ tbw,
                                                  const float* __restrict__ qp,
                                                  const float* __restrict__ kpT,
                                                  const float* __restrict__ xyz,
                                                  const float* __restrict__ refp,
                                                  float* __restrict__ attn) {
  __shared__ __align__(16) u16 tb[64000];     // 125 KB f16 tables
  __shared__ __align__(16) float qrow[2][256];
  __shared__ __align__(16) float rp[2][24];
  __shared__ __align__(16) float red[2][64];  // [qh][h][wave8]
  int t = threadIdx.x;
  int b = blockIdx.x >> 7, qc = blockIdx.x & 127;
  for (int idx = t; idx < 8000; idx += 1024)
    ((uint4*)tb)[idx] = ((const uint4*)tbw)[idx];
  if (t < 128) {
    int qh2 = t >> 6, c = t & 63;
    ((float4*)qrow[qh2])[c] = ((const float4*)(qp + (b * 256 + qc * 2 + qh2) * 256))[c];
  } else if (t < 140) {
    int idx = t - 128;                 // 12 float4s cover rp[2][24]
    int qh2 = idx / 6, c = idx % 6;
    ((float4*)rp[qh2])[c] = ((const float4*)(refp + (b * 256 + qc * 2 + qh2) * 24))[c];
  }
  __syncthreads();

  int wv = t >> 6, l = t & 63;
  int qh = wv >> 3, wvl = wv & 7;
  int q = qc * 2 + qh;
  int k0 = wvl * 256 + l * 4;          // 4 consecutive k per thread
  float acc[8][4] = {};

  // phase 1: qk^T (q pre-scaled)
  const float* kT = kpT + b * (32 * NK);
  #pragma unroll 2
  for (int dq = 0; dq < 8; ++dq) {
    const float* kp0 = kT + (dq * 4) * NK + k0;
    float4 kv0 = *(const float4*)(kp0);
    float4 kv1 = *(const float4*)(kp0 + NK);
    float4 kv2 = *(const float4*)(kp0 + 2 * NK);
    float4 kv3 = *(const float4*)(kp0 + 3 * NK);
    #pragma unroll
    for (int h = 0; h < 8; ++h) {
      float4 qv = *(const float4*)&qrow[qh][h * 32 + dq * 4];
      acc[h][0] = fmaf(qv.x, kv0.x, fmaf(qv.y, kv1.x, fmaf(qv.z, kv2.x, fmaf(qv.w, kv3.x, acc[h][0]))));
      acc[h][1] = fmaf(qv.x, kv0.y, fmaf(qv.y, kv1.y, fmaf(qv.z, kv2.y, fmaf(qv.w, kv3.y, acc[h][1]))));
      acc[h][2] = fmaf(qv.x, kv0.z, fmaf(qv.y, kv1.z, fmaf(qv.z, kv2.z, fmaf(qv.w, kv3.z, acc[h][2]))));
      acc[h][3] = fmaf(qv.x, kv0.w, fmaf(qv.y, kv1.w, fmaf(qv.z, kv2.w, fmaf(qv.w, kv3.w, acc[h][3]))));
    }
  }

  // phase 2: rpe trilinear sampling, accumulate into logits
  {
    const float* xp = xyz + (size_t)(b * NK + k0) * 3;
    float4 X0 = *(const float4*)(xp);
    float4 X1 = *(const float4*)(xp + 4);
    float4 X2 = *(const float4*)(xp + 8);
    float xv[4] = { X0.x, X0.w, X1.z, X2.y };
    float yv[4] = { X0.y, X1.x, X1.w, X2.z };
    float zv[4] = { X0.z, X1.y, X2.x, X2.w };
    #pragma unroll 1
    for (int i = 0; i < 8; ++i) {
      float rx = rp[qh][i * 3 + 0];
      float ry = rp[qh][i * 3 + 1];
      float rz = rp[qh][i * 3 + 2];
      const u16* tp = tb + i * 8000;
      #pragma unroll
      for (int j = 0; j < 4; ++j) {
        Axis ax = axis_setup(rx - xv[j], 8);
        Axis ay = axis_setup(ry - yv[j], 80);
        Axis az = axis_setup(rz - zv[j], 800);
        float w00 = az.w0 * ay.w0, w01 = az.w0 * ay.w1;
        float w10 = az.w1 * ay.w0, w11 = az.w1 * ay.w1;
        U16x8 u;
        u.u = *(const uint4*)(tp + az.o0 + ay.o0 + ax.o0); DO_CORNER(u, w00 * ax.w0, j);
        u.u = *(const uint4*)(tp + az.o0 + ay.o0 + ax.o1); DO_CORNER(u, w00 * ax.w1, j);
        u.u = *(const uint4*)(tp + az.o0 + ay.o1 + ax.o0); DO_CORNER(u, w01 * ax.w0, j);
        u.u = *(const uint4*)(tp + az.o0 + ay.o1 + ax.o1); DO_CORNER(u, w01 * ax.w1, j);
        u.u = *(const uint4*)(tp + az.o1 + ay.o0 + ax.o0); DO_CORNER(u, w10 * ax.w0, j);
        u.u = *(const uint4*)(tp + az.o1 + ay.o0 + ax.o1); DO_CORNER(u, w10 * ax.w1, j);
        u.u = *(const uint4*)(tp + az.o1 + ay.o1 + ax.o0); DO_CORNER(u, w11 * ax.w0, j);
        u.u = *(const uint4*)(tp + az.o1 + ay.o1 + ax.o1); DO_CORNER(u, w11 * ax.w1, j);
      }
    }
  }

  // phase 3: softmax over k (2048) per head, within each wave-half (8 waves)
  float mx[8];
  #pragma unroll
  for (int h = 0; h < 8; ++h) {
    float m = fmaxf(fmaxf(acc[h][0], acc[h][1]), fmaxf(acc[h][2], acc[h][3]));
    #pragma unroll
    for (int off = 32; off >= 1; off >>= 1) m = fmaxf(m, __shfl_xor(m, off, 64));
    mx[h] = m;
  }
  if (l == 0) {
    #pragma unroll
    for (int h = 0; h < 8; ++h) red[qh][h * 8 + wvl] = mx[h];
  }
  __syncthreads();
  #pragma unroll
  for (int h = 0; h < 8; ++h) {
    float4 r0 = *(const float4*)&red[qh][h * 8];
    float4 r1 = *(const float4*)&red[qh][h * 8 + 4];
    mx[h] = fmaxf(fmaxf(fmaxf(r0.x, r0.y), fmaxf(r0.z, r0.w)),
                  fmaxf(fmaxf(r1.x, r1.y), fmaxf(r1.z, r1.w)));
  }
  __syncthreads();
  float sm[8];
  #pragma unroll
  for (int h = 0; h < 8; ++h) {
    acc[h][0] = __expf(acc[h][0] - mx[h]);
    acc[h][1] = __expf(acc[h][1] - mx[h]);
    acc[h][2] = __expf(acc[h][2] - mx[h]);
    acc[h][3] = __expf(acc[h][3] - mx[h]);
    float s = (acc[h][0] + acc[h][1]) + (acc[h][2] + acc[h][3]);
    #pragma unroll
    for (int off = 32; off >= 1; off >>= 1) s += __shfl_xor(s, off, 64);
    sm[h] = s;
  }
  if (l == 0) {
    #pragma unroll
    for (int h = 0; h < 8; ++h) red[qh][h * 8 + wvl] = sm[h];
  }
  __syncthreads();
  #pragma unroll
  for (int h = 0; h < 8; ++h) {
    float4 r0 = *(const float4*)&red[qh][h * 8];
    float4 r1 = *(const float4*)&red[qh][h * 8 + 4];
    float s = ((r0.x + r0.y) + (r0.z + r0.w)) + ((r1.x + r1.y) + (r1.z + r1.w));
    float inv = 1.f / s;
    float4 pv;
    pv.x = acc[h][0] * inv; pv.y = acc[h][1] * inv;
    pv.z = acc[h][2] * inv; pv.w = acc[h][3] * inv;
    *(float4*)&attn[((b * 8 + h) * 256 + q) * 2048 + k0] = pv;
  }
}

// ---------------- kernel 2: x = attn @ v (k-split x8, coalesced) ----------------
#define AV_ACC(A, s, v) { (A).x = fmaf((s), (v).x, (A).x); (A).y = fmaf((s), (v).y, (A).y); \
                          (A).z = fmaf((s), (v).z, (A).z); (A).w = fmaf((s), (v).w, (A).w); }

__global__ __launch_bounds__(256) void k_av(const float* __restrict__ attn,
                                            const float* __restrict__ vp,
                                            float* __restrict__ xpart) {
  int bid = blockIdx.x;  // 512 = b(2) x h(8) x qt(4) x kh(8)
  int kh = bid & 7, qt = (bid >> 3) & 3, h = (bid >> 5) & 7, b = bid >> 8;
  int t = threadIdx.x;
  int qr = t >> 3, dq = t & 7;         // 32 q-pairs x 8 d-quads
  int q0 = qt * 64 + qr * 2;
  const float* ar0 = attn + ((size_t)((b * 8 + h) * 256 + q0)) * 2048 + kh * 256;
  const float* ar1 = ar0 + 2048;
  const float* vbase = vp + ((size_t)(b * NK + kh * 256)) * 32 + dq * 4;
  float4 A0 = {0, 0, 0, 0}, A1 = {0, 0, 0, 0};
  #pragma unroll 4
  for (int k = 0; k < 256; k += 4) {
    float4 a0 = *(const float4*)&ar0[k];          // broadcast across dq lanes
    float4 a1 = *(const float4*)&ar1[k];
    float4 v0 = *(const float4*)&vbase[(k + 0) * 32];  // 8 lanes -> 128B contiguous
    float4 v1 = *(const float4*)&vbase[(k + 1) * 32];
    float4 v2 = *(const float4*)&vbase[(k + 2) * 32];
    float4 v3 = *(const float4*)&vbase[(k + 3) * 32];
    AV_ACC(A0, a0.x, v0) AV_ACC(A0, a0.y, v1) AV_ACC(A0, a0.z, v2) AV_ACC(A0, a0.w, v3)
    AV_ACC(A1, a1.x, v0) AV_ACC(A1, a1.y, v1) AV_ACC(A1, a1.z, v2) AV_ACC(A1, a1.w, v3)
  }
  int o = (b * 256 + q0) * 256 + h * 32 + dq * 4;
  *(float4*)&xpart[kh * 131072 + o] = A0;
  *(float4*)&xpart[kh * 131072 + o + 256] = A1;
}

// ---------------- kernel 3: out = (sum_kh xpart) @ proj_w + proj_b ----------------
__global__ __launch_bounds__(256) void k_out(const float* __restrict__ xpart,
                                             const float* __restrict__ pw,
                                             const float* __restrict__ pb,
                                             float* __restrict__ out) {
  __shared__ float xr[4][257];
  int b = blockIdx.x >> 6, qc = blockIdx.x & 63, t = threadIdx.x;
  for (int idx = t; idx < 1024; idx += 256) {
    int r = idx >> 8, m = idx & 255;
    int q = qc * 4 + r;
    int o = (b * 256 + q) * 256 + m;
    float s = 0.f;
    #pragma unroll
    for (int kh = 0; kh < 8; ++kh) s += xpart[kh * 131072 + o];
    xr[r][m] = s;
  }
  __syncthreads();
  int r = t >> 6, c0 = (t & 63) * 4;
  float4 a = *(const float4*)&pb[c0];
  #pragma unroll 4
  for (int m = 0; m < 256; ++m) {
    float rv = xr[r][m];
    float4 w4 = *(const float4*)&pw[m * 256 + c0];
    a.x = fmaf(rv, w4.x, a.x); a.y = fmaf(rv, w4.y, a.y);
    a.z = fmaf(rv, w4.z, a.z); a.w = fmaf(rv, w4.w, a.w);
  }
  int q = qc * 4 + r;
  *(float4*)&out[(q * BB + b) * 256 + c0] = a;
}

// ---------------- launch ----------------
extern "C" void kernel_launch(void* const* d_in, const int* in_sizes, int n_in,
                              void* d_out, int out_size, void* d_ws, size_t ws_size,
                              hipStream_t stream) {
  const float* query = (const float*)d_in[0];
  const float* key   = (const float*)d_in[1];
  const float* refp  = (const float*)d_in[2];
  // d_in[3] reference_angle: unused by reference
  const float* xyz   = (const float*)d_in[4];
  const float* qw    = (const float*)d_in[5];
  const float* qb    = (const float*)d_in[6];
  const float* kw    = (const float*)d_in[7];
  const float* kb    = (const float*)d_in[8];
  const float* vw    = (const float*)d_in[9];
  const float* vb    = (const float*)d_in[10];
  const float* pw    = (const float*)d_in[11];
  const float* pb    = (const float*)d_in[12];
  const float* w1    = (const float*)d_in[13];
  const float* b1    = (const float*)d_in[14];
  const float* w2    = (const float*)d_in[15];

  char* ws = (char*)d_ws;
  u16*   tb    = (u16*)(ws + TB_OFF);
  float* qp    = (float*)(ws + QP_OFF);
  float* kpT   = (float*)(ws + KT_OFF);
  float* vp    = (float*)(ws + VP_OFF);
  float* xpart = (float*)(ws + X_OFF);
  float* out  = (float*)d_out;
  float* attn = out + 131072;  // second tuple output

  hipLaunchKernelGGL(k_prep, dim3(328), dim3(512),  0, stream,
                     query, key, qw, qb, kw, kb, vw, vb, w1, b1, w2, tb, qp, kpT, vp);
  hipLaunchKernelGGL(k_main, dim3(256), dim3(1024), 0, stream, tb, qp, kpT, xyz, refp, attn);
  hipLaunchKernelGGL(k_av,   dim3(512), dim3(256),  0, stream, attn, vp, xpart);
  hipLaunchKernelGGL(k_out,  dim3(128), dim3(256),  0, stream, xpart, pw, pb, out);
}

// Round 6
// 193.648 us; speedup vs baseline: 1.7253x; 1.1236x over previous
//
#include <hip/hip_runtime.h>
#include <hip/hip_bf16.h>
#include <cstdint>

#define NQ 256
#define NK 2048
#define BB 2
#define SCALE 0.17677669529663687f  // 32^-0.5

// ws byte offsets (16B aligned)
#define TB_OFF 0u         // f16[64000]   tables [i][z][y][x][h]          128000 B
#define QP_OFF 128000u    // float[131072]  q-proj (B,nQ,256), pre-scaled 524288 B
#define KT_OFF 652288u    // float[131072]  k-proj transposed (B,32,nK)   524288 B
#define VP_OFF 1176576u   // float[131072]  v-proj (B,nK,32)              524288 B

typedef unsigned short u16;
typedef _Float16 h16;
union U16x8 { uint4 u; h16 h[8]; };

// ---------------- kernel 0: fused prep (tables + kv-proj + q-proj) ----------------
// blocks [0,256): kv-proj   [256,320): q-proj   [320,352): cpb tables (8 i x 4 cc)
__global__ __launch_bounds__(512) void k_prep(const float* __restrict__ query,
                                              const float* __restrict__ key,
                                              const float* __restrict__ qw,
                                              const float* __restrict__ qb,
                                              const float* __restrict__ kw,
                                              const float* __restrict__ kb,
                                              const float* __restrict__ vw,
                                              const float* __restrict__ vb,
                                              const float* __restrict__ w1g,
                                              const float* __restrict__ b1g,
                                              const float* __restrict__ w2g,
                                              u16* __restrict__ tb,
                                              float* __restrict__ qp,
                                              float* __restrict__ kpT,
                                              float* __restrict__ vp) {
  __shared__ __align__(16) char smraw[16 * 257 * 4];
  int bid = blockIdx.x, t = threadIdx.x;

  if (bid < 256) {
    // ---- kv-proj: kpT[b][d][k] (LDS-transposed), vp[b][k][d] (direct) ----
    float (*rows)[257] = (float(*)[257])smraw;
    int b = bid >> 7, kc = bid & 127;
    for (int idx = t; idx < 4096; idx += 512) {
      int r = idx >> 8, m = idx & 255;
      rows[r][m] = key[((kc * 16 + r) * BB + b) * 256 + m];
    }
    __syncthreads();
    int ks = t >> 5, d = t & 31;
    float a = kb[d], av = vb[d];
    #pragma unroll 4
    for (int m = 0; m < 256; ++m) {
      float rv = rows[ks][m];
      a  = fmaf(rv, kw[m * 32 + d], a);
      av = fmaf(rv, vw[m * 32 + d], av);
    }
    int k = kc * 16 + ks;
    vp[(b * NK + k) * 32 + d] = av;        // coalesced: d consecutive across lanes
    __syncthreads();                       // rows no longer needed
    float* f1 = (float*)smraw;             // 512 floats
    f1[d * 16 + ks] = a;
    __syncthreads();
    int dd = t >> 4, kk = t & 15;          // 512 threads cover 32x16
    kpT[(b * 32 + dd) * NK + kc * 16 + kk] = f1[dd * 16 + kk];
  } else if (bid < 320) {
    // ---- q-proj (pre-scaled): 8 rows per block ----
    float (*rows)[257] = (float(*)[257])smraw;
    int qg = bid - 256;  // 0..63, 8 global rows each
    for (int idx = t; idx < 2048; idx += 512) {
      int r = idx >> 8, m = idx & 255;
      int g = qg * 8 + r, b = g >> 8, q = g & 255;
      rows[r][m] = query[(q * BB + b) * 256 + m];
    }
    __syncthreads();
    int r = t >> 6, c0 = (t & 63) * 4;
    int g = qg * 8 + r;
    float4 acc = *(const float4*)&qb[c0];
    #pragma unroll 4
    for (int m = 0; m < 256; ++m) {
      float rv = rows[r][m];
      float4 w4 = *(const float4*)&qw[m * 256 + c0];
      acc.x = fmaf(rv, w4.x, acc.x); acc.y = fmaf(rv, w4.y, acc.y);
      acc.z = fmaf(rv, w4.z, acc.z); acc.w = fmaf(rv, w4.w, acc.w);
    }
    float4 o; o.x = acc.x * SCALE; o.y = acc.y * SCALE; o.z = acc.z * SCALE; o.w = acc.w * SCALE;
    *(float4*)&qp[g * 256 + c0] = o;
  } else {
    // ---- cpb tables (f16): 32 blocks = 8 i x 4 cc, 250 cells each ----
    float* w1 = (float*)smraw;          // 384
    float* b1 = w1 + 384;               // 128
    float* w2 = b1 + 128;               // 1024
    int ib = bid - 320;
    int i = ib >> 2, cc = ib & 3;
    for (int idx = t; idx < 384; idx += 512) w1[idx] = w1g[i * 384 + idx];
    if (t < 128) b1[t] = b1g[i * 128 + t];
    for (int idx = t; idx < 1024; idx += 512) w2[idx] = w2g[i * 1024 + idx];
    __syncthreads();
    if (t < 250) {
      int cell = cc * 250 + t;
      int z = cell / 100, y = (cell / 10) % 10, x = cell % 10;
      const float step = 8.0f / 9.0f;
      float cz = -4.f + z * step, cy = -4.f + y * step, cx = -4.f + x * step;
      float o0 = 0, o1 = 0, o2 = 0, o3 = 0, o4 = 0, o5 = 0, o6 = 0, o7 = 0;
      for (int d = 0; d < 128; ++d) {
        float h = fmaxf(fmaf(cz, w1[d], fmaf(cy, w1[128 + d], fmaf(cx, w1[256 + d], b1[d]))), 0.f);
        const float* w2r = &w2[d * 8];
        o0 = fmaf(h, w2r[0], o0); o1 = fmaf(h, w2r[1], o1);
        o2 = fmaf(h, w2r[2], o2); o3 = fmaf(h, w2r[3], o3);
        o4 = fmaf(h, w2r[4], o4); o5 = fmaf(h, w2r[5], o5);
        o6 = fmaf(h, w2r[6], o6); o7 = fmaf(h, w2r[7], o7);
      }
      U16x8 R;
      R.h[0] = (h16)o0; R.h[1] = (h16)o1; R.h[2] = (h16)o2; R.h[3] = (h16)o3;
      R.h[4] = (h16)o4; R.h[5] = (h16)o5; R.h[6] = (h16)o6; R.h[7] = (h16)o7;
      *(uint4*)&tb[i * 8000 + cell * 8] = R.u;
    }
  }
}

// ---------------- kernel 1: mega (qk + rpe + softmax + attn-out + av + proj) ----------------
struct Axis { int o0, o1; float w0, w1; };

static __device__ __forceinline__ Axis axis_setup(float dv, int stride) {
  float g = copysignf(__log2f(fmaf(fabsf(dv), 512.f, 1.f)) * (1.f / 12.f), dv);
  float p = fmaf(g, 4.5f, 4.5f);
  float f = floorf(p);
  int i0 = (int)f;
  float w1v = p - f;
  float w0v = 1.f - w1v;
  Axis a;
  a.w0 = ((unsigned)i0 <= 9u) ? w0v : 0.f;
  a.w1 = ((unsigned)(i0 + 1) <= 9u) ? w1v : 0.f;
  int c0 = min(max(i0, 0), 9);
  int c1 = min(max(i0 + 1, 0), 9);
  a.o0 = c0 * stride;
  a.o1 = c1 * stride;
  return a;
}

#define DO_CORNER(CU, W, J) do { float ww = (W); \
  acc[0][J] = fmaf((float)(CU).h[0], ww, acc[0][J]); \
  acc[1][J] = fmaf((float)(CU).h[1], ww, acc[1][J]); \
  acc[2][J] = fmaf((float)(CU).h[2], ww, acc[2][J]); \
  acc[3][J] = fmaf((float)(CU).h[3], ww, acc[3][J]); \
  acc[4][J] = fmaf((float)(CU).h[4], ww, acc[4][J]); \
  acc[5][J] = fmaf((float)(CU).h[5], ww, acc[5][J]); \
  acc[6][J] = fmaf((float)(CU).h[6], ww, acc[6][J]); \
  acc[7][J] = fmaf((float)(CU).h[7], ww, acc[7][J]); } while (0)

__global__ __launch_bounds__(1024, 4) void k_mega(const u16* __restrict__ tbw,
                                                  const float* __restrict__ qp,
                                                  const float* __restrict__ kpT,
                                                  const float* __restrict__ xyz,
                                                  const float* __restrict__ refp,
                                                  const float* __restrict__ vp,
                                                  const float* __restrict__ pw,
                                                  const float* __restrict__ pb,
                                                  float* __restrict__ attn,
                                                  float* __restrict__ out) {
  // un: phase 1-2 = f16 tables (125 KB); phase 3.5+ = p f32 [2][8][2048] (128 KB)
  __shared__ __align__(16) char un[131072];
  __shared__ __align__(16) float red4[2][8][8][32];  // 16 KB: [qh][chunk][h][d] partials / proj scratch
  __shared__ __align__(16) float qrow[2][256];       // q rows, later x rows
  __shared__ __align__(16) float rp[2][24];
  __shared__ __align__(16) float red[2][64];
  u16* tb = (u16*)un;
  float* p = (float*)un;

  int t = threadIdx.x;
  int b = blockIdx.x >> 7, qc = blockIdx.x & 127;
  for (int idx = t; idx < 8000; idx += 1024)
    ((uint4*)tb)[idx] = ((const uint4*)tbw)[idx];
  if (t < 128) {
    int qh2 = t >> 6, c = t & 63;
    ((float4*)qrow[qh2])[c] = ((const float4*)(qp + (b * 256 + qc * 2 + qh2) * 256))[c];
  } else if (t < 140) {
    int idx = t - 128;                 // 12 float4s cover rp[2][24]
    int qh2 = idx / 6, c = idx % 6;
    ((float4*)rp[qh2])[c] = ((const float4*)(refp + (b * 256 + qc * 2 + qh2) * 24))[c];
  }
  __syncthreads();

  int wv = t >> 6, l = t & 63;
  int qh = wv >> 3, wvl = wv & 7;
  int k0 = wvl * 256 + l * 4;          // 4 consecutive k per thread
  float acc[8][4] = {};

  // phase 1: qk^T (q pre-scaled)
  const float* kT = kpT + b * (32 * NK);
  #pragma unroll 2
  for (int dq = 0; dq < 8; ++dq) {
    const float* kp0 = kT + (dq * 4) * NK + k0;
    float4 kv0 = *(const float4*)(kp0);
    float4 kv1 = *(const float4*)(kp0 + NK);
    float4 kv2 = *(const float4*)(kp0 + 2 * NK);
    float4 kv3 = *(const float4*)(kp0 + 3 * NK);
    #pragma unroll
    for (int h = 0; h < 8; ++h) {
      float4 qv = *(const float4*)&qrow[qh][h * 32 + dq * 4];
      acc[h][0] = fmaf(qv.x, kv0.x, fmaf(qv.y, kv1.x, fmaf(qv.z, kv2.x, fmaf(qv.w, kv3.x, acc[h][0]))));
      acc[h][1] = fmaf(qv.x, kv0.y, fmaf(qv.y, kv1.y, fmaf(qv.z, kv2.y, fmaf(qv.w, kv3.y, acc[h][1]))));
      acc[h][2] = fmaf(qv.x, kv0.z, fmaf(qv.y, kv1.z, fmaf(qv.z, kv2.z, fmaf(qv.w, kv3.z, acc[h][2]))));
      acc[h][3] = fmaf(qv.x, kv0.w, fmaf(qv.y, kv1.w, fmaf(qv.z, kv2.w, fmaf(qv.w, kv3.w, acc[h][3]))));
    }
  }

  // phase 2: rpe trilinear sampling, accumulate into logits
  {
    const float* xp = xyz + (size_t)(b * NK + k0) * 3;
    float4 X0 = *(const float4*)(xp);
    float4 X1 = *(const float4*)(xp + 4);
    float4 X2 = *(const float4*)(xp + 8);
    float xv[4] = { X0.x, X0.w, X1.z, X2.y };
    float yv[4] = { X0.y, X1.x, X1.w, X2.z };
    float zv[4] = { X0.z, X1.y, X2.x, X2.w };
    #pragma unroll 1
    for (int i = 0; i < 8; ++i) {
      float rx = rp[qh][i * 3 + 0];
      float ry = rp[qh][i * 3 + 1];
      float rz = rp[qh][i * 3 + 2];
      const u16* tp = tb + i * 8000;
      #pragma unroll
      for (int j = 0; j < 4; ++j) {
        Axis ax = axis_setup(rx - xv[j], 8);
        Axis ay = axis_setup(ry - yv[j], 80);
        Axis az = axis_setup(rz - zv[j], 800);
        float w00 = az.w0 * ay.w0, w01 = az.w0 * ay.w1;
        float w10 = az.w1 * ay.w0, w11 = az.w1 * ay.w1;
        U16x8 u;
        u.u = *(const uint4*)(tp + az.o0 + ay.o0 + ax.o0); DO_CORNER(u, w00 * ax.w0, j);
        u.u = *(const uint4*)(tp + az.o0 + ay.o0 + ax.o1); DO_CORNER(u, w00 * ax.w1, j);
        u.u = *(const uint4*)(tp + az.o0 + ay.o1 + ax.o0); DO_CORNER(u, w01 * ax.w0, j);
        u.u = *(const uint4*)(tp + az.o0 + ay.o1 + ax.o1); DO_CORNER(u, w01 * ax.w1, j);
        u.u = *(const uint4*)(tp + az.o1 + ay.o0 + ax.o0); DO_CORNER(u, w10 * ax.w0, j);
        u.u = *(const uint4*)(tp + az.o1 + ay.o0 + ax.o1); DO_CORNER(u, w10 * ax.w1, j);
        u.u = *(const uint4*)(tp + az.o1 + ay.o1 + ax.o0); DO_CORNER(u, w11 * ax.w0, j);
        u.u = *(const uint4*)(tp + az.o1 + ay.o1 + ax.o1); DO_CORNER(u, w11 * ax.w1, j);
      }
    }
  }

  // phase 3: softmax over k (2048) per head (8 waves per qh)
  float mx[8];
  #pragma unroll
  for (int h = 0; h < 8; ++h) {
    float m = fmaxf(fmaxf(acc[h][0], acc[h][1]), fmaxf(acc[h][2], acc[h][3]));
    #pragma unroll
    for (int off = 32; off >= 1; off >>= 1) m = fmaxf(m, __shfl_xor(m, off, 64));
    mx[h] = m;
  }
  if (l == 0) {
    #pragma unroll
    for (int h = 0; h < 8; ++h) red[qh][h * 8 + wvl] = mx[h];
  }
  __syncthreads();   // NOTE: last table (tb) read was in phase 2; after this sync un[] may be reused
  #pragma unroll
  for (int h = 0; h < 8; ++h) {
    float4 r0 = *(const float4*)&red[qh][h * 8];
    float4 r1 = *(const float4*)&red[qh][h * 8 + 4];
    mx[h] = fmaxf(fmaxf(fmaxf(r0.x, r0.y), fmaxf(r0.z, r0.w)),
                  fmaxf(fmaxf(r1.x, r1.y), fmaxf(r1.z, r1.w)));
  }
  __syncthreads();
  float sm[8];
  #pragma unroll
  for (int h = 0; h < 8; ++h) {
    acc[h][0] = __expf(acc[h][0] - mx[h]);
    acc[h][1] = __expf(acc[h][1] - mx[h]);
    acc[h][2] = __expf(acc[h][2] - mx[h]);
    acc[h][3] = __expf(acc[h][3] - mx[h]);
    float s = (acc[h][0] + acc[h][1]) + (acc[h][2] + acc[h][3]);
    #pragma unroll
    for (int off = 32; off >= 1; off >>= 1) s += __shfl_xor(s, off, 64);
    sm[h] = s;
  }
  if (l == 0) {
    #pragma unroll
    for (int h = 0; h < 8; ++h) red[qh][h * 8 + wvl] = sm[h];
  }
  __syncthreads();
  // phase 3.5: normalize and store p into LDS (overwrites table region)
  #pragma unroll
  for (int h = 0; h < 8; ++h) {
    float4 r0 = *(const float4*)&red[qh][h * 8];
    float4 r1 = *(const float4*)&red[qh][h * 8 + 4];
    float s = ((r0.x + r0.y) + (r0.z + r0.w)) + ((r1.x + r1.y) + (r1.z + r1.w));
    float inv = 1.f / s;
    float4 pv;
    pv.x = acc[h][0] * inv; pv.y = acc[h][1] * inv;
    pv.z = acc[h][2] * inv; pv.w = acc[h][3] * inv;
    *(float4*)&p[(qh * 8 + h) * 2048 + k0] = pv;
  }
  __syncthreads();

  // phase 3.6: coalesced attn writeout from LDS (32768 floats)
  #pragma unroll
  for (int c = 0; c < 8; ++c) {
    int flat = (c * 1024 + t) * 4;
    int qh2 = flat >> 14, h2 = (flat >> 11) & 7, kk = flat & 2047;
    float4 pv4 = *(const float4*)&p[(qh2 * 8 + h2) * 2048 + kk];
    *(float4*)&attn[((size_t)((b * 8 + h2) * 256 + (qc * 2 + qh2))) * 2048 + kk] = pv4;
  }

  // phase 4: x = p @ v.  wave = (chunk, qh); lane = (ks2, dq); 256 k per wave
  {
    int ch = wv >> 1, pqh = wv & 1;          // 8 chunks x 2 qh
    int ks2 = l >> 3, dq = l & 7;
    float a2[8][4] = {};
    const float* vbase = vp + ((size_t)(b * NK + ch * 256)) * 32 + dq * 4;
    const float* prow = p + pqh * 16384 + ch * 256;
    #pragma unroll 2
    for (int kk = 0; kk < 32; ++kk) {
      int ko = kk * 8 + ks2;
      float4 v4 = *(const float4*)&vbase[ko * 32];
      #pragma unroll
      for (int h = 0; h < 8; ++h) {
        float pvv = prow[h * 2048 + ko];
        a2[h][0] = fmaf(pvv, v4.x, a2[h][0]);
        a2[h][1] = fmaf(pvv, v4.y, a2[h][1]);
        a2[h][2] = fmaf(pvv, v4.z, a2[h][2]);
        a2[h][3] = fmaf(pvv, v4.w, a2[h][3]);
      }
    }
    // reduce over ks2 (lane bits 3..5)
    #pragma unroll
    for (int off = 8; off <= 32; off <<= 1) {
      #pragma unroll
      for (int h = 0; h < 8; ++h) {
        a2[h][0] += __shfl_xor(a2[h][0], off, 64);
        a2[h][1] += __shfl_xor(a2[h][1], off, 64);
        a2[h][2] += __shfl_xor(a2[h][2], off, 64);
        a2[h][3] += __shfl_xor(a2[h][3], off, 64);
      }
    }
    if (ks2 == 0) {
      #pragma unroll
      for (int h = 0; h < 8; ++h) {
        float4 w4; w4.x = a2[h][0]; w4.y = a2[h][1]; w4.z = a2[h][2]; w4.w = a2[h][3];
        *(float4*)&red4[pqh][ch][h][dq * 4] = w4;
      }
    }
  }
  __syncthreads();
  // reduce 8 chunks -> x rows (reuse qrow)
  if (t < 512) {
    int pqh = t >> 8, m = t & 255;
    int h = m >> 5, d = m & 31;
    float s = 0.f;
    #pragma unroll
    for (int ch = 0; ch < 8; ++ch) s += red4[pqh][ch][h][d];
    qrow[pqh][m] = s;
  }
  __syncthreads();

  // phase 5: out = x @ pw + pb
  {
    float* scratch = (float*)red4;          // [2 qh][2 half][256]
    int c = t & 255, half = (t >> 8) & 1, pqh = t >> 9;
    int m0 = half * 128;
    float a = 0.f;
    #pragma unroll 4
    for (int m = 0; m < 128; ++m) {
      a = fmaf(qrow[pqh][m0 + m], pw[(m0 + m) * 256 + c], a);
    }
    scratch[(pqh * 2 + half) * 256 + c] = a;
  }
  __syncthreads();
  if (t < 512) {
    float* scratch = (float*)red4;
    int pqh = t >> 8, c = t & 255;
    float v = scratch[(pqh * 2) * 256 + c] + scratch[(pqh * 2 + 1) * 256 + c] + pb[c];
    int q = qc * 2 + pqh;
    out[(q * BB + b) * 256 + c] = v;
  }
}

// ---------------- launch ----------------
extern "C" void kernel_launch(void* const* d_in, const int* in_sizes, int n_in,
                              void* d_out, int out_size, void* d_ws, size_t ws_size,
                              hipStream_t stream) {
  const float* query = (const float*)d_in[0];
  const float* key   = (const float*)d_in[1];
  const float* refp  = (const float*)d_in[2];
  // d_in[3] reference_angle: unused by reference
  const float* xyz   = (const float*)d_in[4];
  const float* qw    = (const float*)d_in[5];
  const float* qb    = (const float*)d_in[6];
  const float* kw    = (const float*)d_in[7];
  const float* kb    = (const float*)d_in[8];
  const float* vw    = (const float*)d_in[9];
  const float* vb    = (const float*)d_in[10];
  const float* pw    = (const float*)d_in[11];
  const float* pb    = (const float*)d_in[12];
  const float* w1    = (const float*)d_in[13];
  const float* b1    = (const float*)d_in[14];
  const float* w2    = (const float*)d_in[15];

  char* ws = (char*)d_ws;
  u16*   tb  = (u16*)(ws + TB_OFF);
  float* qp  = (float*)(ws + QP_OFF);
  float* kpT = (float*)(ws + KT_OFF);
  float* vp  = (float*)(ws + VP_OFF);
  float* out  = (float*)d_out;
  float* attn = out + 131072;  // second tuple output

  hipLaunchKernelGGL(k_prep, dim3(352), dim3(512),  0, stream,
                     query, key, qw, qb, kw, kb, vw, vb, w1, b1, w2, tb, qp, kpT, vp);
  hipLaunchKernelGGL(k_mega, dim3(256), dim3(1024), 0, stream,
                     tb, qp, kpT, xyz, refp, vp, pw, pb, attn, out);
}